// Round 1
// baseline (172.967 us; speedup 1.0000x reference)
//
#include <hip/hip_runtime.h>

// FeaturesLinear: out[b,:] = sum_{h<50} user_W[fid[b,h]] * rating_W[ridx[b,h]]
//                            + item_W[item_ids[b]] + bias
// B=16384, HIST=50, D=128. Segments are contiguous (repeat(arange(B), 50)).

#define BATCH     16384
#define HIST      50
#define DIM4      32          // 128 floats = 32 float4
#define ROWS      8           // batch rows per block
#define BLOCK     256         // ROWS * 32 lanes

__global__ __launch_bounds__(BLOCK) void features_linear_kernel(
    const int*    __restrict__ feature_ids,   // [TOTAL]
    const float*  __restrict__ ratings,       // [TOTAL]
    const int*    __restrict__ item_ids,      // [BATCH]
    const float4* __restrict__ user_W,        // [100001, 32] as float4
    const float4* __restrict__ rating_W,      // [10, 32] as float4
    const float4* __restrict__ item_W,        // [100000, 32] as float4
    const float4* __restrict__ bias,          // [32] as float4
    float4*       __restrict__ out)           // [BATCH, 32] as float4
{
    __shared__ float4 sh_rW[10 * DIM4];       // 5 KB: full rating_W table
    __shared__ int    sh_fid[ROWS * HIST];    // this block's feature ids
    __shared__ int    sh_ridx[ROWS * HIST];   // this block's rating indices

    const int tid = threadIdx.x;

    // Stage rating_W (320 float4, coalesced)
    for (int i = tid; i < 10 * DIM4; i += BLOCK) sh_rW[i] = rating_W[i];

    // Stage this block's 400 ids + rating indices
    const int base = blockIdx.x * (ROWS * HIST);
    for (int i = tid; i < ROWS * HIST; i += BLOCK) {
        sh_fid[i] = feature_ids[base + i];
        float r = ratings[base + i];
        // ratings are exact multiples of 0.5 in [0.5, 5.0]; r*2 is an exact
        // integer in [1,10] -> index = r*2 - 1 in [0,9]. Exact, no fp edge.
        sh_ridx[i] = (int)(r * 2.0f) - 1;
    }
    __syncthreads();

    const int row = tid >> 5;        // 0..7 within block
    const int d4  = tid & 31;        // float4 index within the 128-dim row
    const int b   = blockIdx.x * ROWS + row;

    float4 acc; acc.x = 0.f; acc.y = 0.f; acc.z = 0.f; acc.w = 0.f;
    const int off = row * HIST;

    for (int h = 0; h < HIST; ++h) {
        const int fid  = sh_fid[off + h];   // wave-broadcast LDS read (free)
        const int ridx = sh_ridx[off + h];
        const float4 u  = user_W[fid * DIM4 + d4];   // 512B coalesced row read
        const float4 rw = sh_rW[ridx * DIM4 + d4];   // ds_read_b128
        acc.x += u.x * rw.x;
        acc.y += u.y * rw.y;
        acc.z += u.z * rw.z;
        acc.w += u.w * rw.w;
    }

    const int iid = item_ids[b];
    const float4 iw = item_W[iid * DIM4 + d4];
    const float4 bs = bias[d4];

    float4 o;
    o.x = acc.x + iw.x + bs.x;
    o.y = acc.y + iw.y + bs.y;
    o.z = acc.z + iw.z + bs.z;
    o.w = acc.w + iw.w + bs.w;
    out[b * DIM4 + d4] = o;
}

extern "C" void kernel_launch(void* const* d_in, const int* in_sizes, int n_in,
                              void* d_out, int out_size, void* d_ws, size_t ws_size,
                              hipStream_t stream) {
    const int*    feature_ids = (const int*)   d_in[0];
    const float*  ratings     = (const float*) d_in[1];
    // d_in[2] = segment_ids: unused (segments are contiguous by construction)
    const int*    item_ids    = (const int*)   d_in[3];
    const float4* user_W      = (const float4*)d_in[4];
    const float4* rating_W    = (const float4*)d_in[5];
    const float4* item_W      = (const float4*)d_in[6];
    const float4* bias        = (const float4*)d_in[7];
    float4*       out         = (float4*)      d_out;

    dim3 grid(BATCH / ROWS);   // 2048 blocks
    dim3 block(BLOCK);
    features_linear_kernel<<<grid, block, 0, stream>>>(
        feature_ids, ratings, item_ids, user_W, rating_W, item_W, bias, out);
}

// Round 2
// 172.546 us; speedup vs baseline: 1.0024x; 1.0024x over previous
//
#include <hip/hip_runtime.h>

// FeaturesLinear: out[b,:] = sum_{h<50} user_W[fid[b,h]] * rating_W[ridx[b,h]]
//                            + item_W[item_ids[b]] + bias
// B=16384, HIST=50, D=128. Segments are contiguous (repeat(arange(B), 50)).
//
// R1: latency-bound at 62us (3.3 TB/s, VGPR=32, ~2 loads in flight).
// R2: unroll h-loop x5 -> 5 independent user_W gathers in flight per wave.
//     Keep VGPR <= 64 to hold 8 waves/SIMD.

#define BATCH     16384
#define HIST      50
#define UNROLL    5
#define DIM4      32          // 128 floats = 32 float4
#define ROWS      8           // batch rows per block
#define BLOCK     256         // ROWS * 32 lanes

__global__ __launch_bounds__(BLOCK) void features_linear_kernel(
    const int*    __restrict__ feature_ids,   // [TOTAL]
    const float*  __restrict__ ratings,       // [TOTAL]
    const int*    __restrict__ item_ids,      // [BATCH]
    const float4* __restrict__ user_W,        // [100001, 32] as float4
    const float4* __restrict__ rating_W,      // [10, 32] as float4
    const float4* __restrict__ item_W,        // [100000, 32] as float4
    const float4* __restrict__ bias,          // [32] as float4
    float4*       __restrict__ out)           // [BATCH, 32] as float4
{
    __shared__ float4 sh_rW[10 * DIM4];       // 5 KB: full rating_W table
    __shared__ int    sh_fid[ROWS * HIST];    // this block's feature ids
    __shared__ int    sh_ridx[ROWS * HIST];   // this block's rating indices

    const int tid = threadIdx.x;

    // Stage rating_W (320 float4, coalesced)
    for (int i = tid; i < 10 * DIM4; i += BLOCK) sh_rW[i] = rating_W[i];

    // Stage this block's 400 ids + rating indices
    const int base = blockIdx.x * (ROWS * HIST);
    for (int i = tid; i < ROWS * HIST; i += BLOCK) {
        sh_fid[i] = feature_ids[base + i];
        float r = ratings[base + i];
        // ratings are exact multiples of 0.5 in [0.5,5.0]; r*2 is an exact
        // integer in [1,10] -> index r*2-1 in [0,9]. Exact, no fp edge.
        sh_ridx[i] = (int)(r * 2.0f) - 1;
    }
    __syncthreads();

    const int row = tid >> 5;        // 0..7 within block
    const int d4  = tid & 31;        // float4 index within the 128-dim row
    const int b   = blockIdx.x * ROWS + row;

    // Prefetch the epilogue loads early so they overlap the gather loop.
    const int    iid = item_ids[b];
    const float4 iw  = item_W[iid * DIM4 + d4];
    const float4 bs  = bias[d4];

    float4 acc; acc.x = 0.f; acc.y = 0.f; acc.z = 0.f; acc.w = 0.f;
    const int off = row * HIST;

    for (int h = 0; h < HIST; h += UNROLL) {
        // Gather 5 indices (wave-broadcast LDS reads, free)
        const int f0 = sh_fid[off + h + 0], r0 = sh_ridx[off + h + 0];
        const int f1 = sh_fid[off + h + 1], r1 = sh_ridx[off + h + 1];
        const int f2 = sh_fid[off + h + 2], r2 = sh_ridx[off + h + 2];
        const int f3 = sh_fid[off + h + 3], r3 = sh_ridx[off + h + 3];
        const int f4 = sh_fid[off + h + 4], r4 = sh_ridx[off + h + 4];

        // 5 independent 512B coalesced gathers in flight
        const float4 u0 = user_W[f0 * DIM4 + d4];
        const float4 u1 = user_W[f1 * DIM4 + d4];
        const float4 u2 = user_W[f2 * DIM4 + d4];
        const float4 u3 = user_W[f3 * DIM4 + d4];
        const float4 u4 = user_W[f4 * DIM4 + d4];

        const float4 w0 = sh_rW[r0 * DIM4 + d4];
        const float4 w1 = sh_rW[r1 * DIM4 + d4];
        const float4 w2 = sh_rW[r2 * DIM4 + d4];
        const float4 w3 = sh_rW[r3 * DIM4 + d4];
        const float4 w4 = sh_rW[r4 * DIM4 + d4];

        acc.x += u0.x * w0.x; acc.y += u0.y * w0.y; acc.z += u0.z * w0.z; acc.w += u0.w * w0.w;
        acc.x += u1.x * w1.x; acc.y += u1.y * w1.y; acc.z += u1.z * w1.z; acc.w += u1.w * w1.w;
        acc.x += u2.x * w2.x; acc.y += u2.y * w2.y; acc.z += u2.z * w2.z; acc.w += u2.w * w2.w;
        acc.x += u3.x * w3.x; acc.y += u3.y * w3.y; acc.z += u3.z * w3.z; acc.w += u3.w * w3.w;
        acc.x += u4.x * w4.x; acc.y += u4.y * w4.y; acc.z += u4.z * w4.z; acc.w += u4.w * w4.w;
    }

    float4 o;
    o.x = acc.x + iw.x + bs.x;
    o.y = acc.y + iw.y + bs.y;
    o.z = acc.z + iw.z + bs.z;
    o.w = acc.w + iw.w + bs.w;
    out[b * DIM4 + d4] = o;
}

extern "C" void kernel_launch(void* const* d_in, const int* in_sizes, int n_in,
                              void* d_out, int out_size, void* d_ws, size_t ws_size,
                              hipStream_t stream) {
    const int*    feature_ids = (const int*)   d_in[0];
    const float*  ratings     = (const float*) d_in[1];
    // d_in[2] = segment_ids: unused (segments are contiguous by construction)
    const int*    item_ids    = (const int*)   d_in[3];
    const float4* user_W      = (const float4*)d_in[4];
    const float4* rating_W    = (const float4*)d_in[5];
    const float4* item_W      = (const float4*)d_in[6];
    const float4* bias        = (const float4*)d_in[7];
    float4*       out         = (float4*)      d_out;

    dim3 grid(BATCH / ROWS);   // 2048 blocks
    dim3 block(BLOCK);
    features_linear_kernel<<<grid, block, 0, stream>>>(
        feature_ids, ratings, item_ids, user_W, rating_W, item_W, bias, out);
}